// Round 7
// baseline (554.029 us; speedup 1.0000x reference)
//
#include <hip/hip_runtime.h>
#include <hip/hip_bf16.h>

#define BATCH 2048
#define KD 1024
#define ND 1024
#define NLEAF 64
#define BM 256
#define BN 256
// GEMM runs 32 kk-steps of K=32 each (K=1024)

typedef __attribute__((ext_vector_type(8))) short bf16x8;
typedef __attribute__((ext_vector_type(4))) float f32x4;
typedef __attribute__((ext_vector_type(4))) _Float16 f16x4;

// workspace layout (bytes)
#define WLB_OFF 0ULL                 // B (Wl) bf16 row-major, 128 MB
#define XP_OFF  134217728ULL         // A (x) bf16 fragment-packed, 4 MB
#define RT_OFF  138412032ULL         // routing 512 KB
#define LG_OFF  138936320ULL         // logits fp16 (268 MB full / 64 MB grouped)

__device__ __forceinline__ unsigned short f2bf(float f) {
  unsigned int u = __float_as_uint(f);
  u += 0x7fffu + ((u >> 16) & 1u);
  return (unsigned short)(u >> 16);
}

__device__ __forceinline__ void gload_lds16(const void* g, void* l) {
  __builtin_amdgcn_global_load_lds(
      (const __attribute__((address_space(1))) unsigned int*)g,
      (__attribute__((address_space(3))) unsigned int*)l, 16, 0, 0);
}

// -------- kernel 1: f32 -> bf16; Wl row-major, x fragment-packed -----------
// A-pack mapping (must mirror GEMM consumption): element (row,k) ->
//   f = (k>>5)*128 + (row>>4); lane = ((k>>3)&3)*16 + (row&15); e = k&7
//   ushort offset = f*512 + lane*8 + e
__global__ void __launch_bounds__(256) convert_kernel(
    const float* __restrict__ Wl, const float* __restrict__ x,
    unsigned short* __restrict__ wlb, unsigned short* __restrict__ xp) {
  const long long WL4 = 16777216LL;   // 64M Wl elems / 4
  const long long XJ  = 524288LL;     // 2M x elems / 4
  long long i = (long long)blockIdx.x * 256 + threadIdx.x;
  const long long stride = (long long)gridDim.x * 256;
  for (; i < WL4 + XJ; i += stride) {
    if (i < WL4) {
      float4 v = ((const float4*)Wl)[i];
      ushort4 o;
      o.x = f2bf(v.x); o.y = f2bf(v.y); o.z = f2bf(v.z); o.w = f2bf(v.w);
      ((ushort4*)wlb)[i] = o;
    } else {
      const long long jj = i - WL4;
      const int pt = (int)(jj >> 1), half = (int)(jj & 1);
      const int f = pt >> 6, l = pt & 63;
      const int row = (f & 127) * 16 + (l & 15);
      const int k0 = (f >> 7) * 32 + (l >> 4) * 8 + half * 4;
      float4 v = *(const float4*)(x + (size_t)row * KD + k0);
      ushort4 o;
      o.x = f2bf(v.x); o.y = f2bf(v.y); o.z = f2bf(v.z); o.w = f2bf(v.w);
      *(ushort4*)(xp + (size_t)f * 512 + l * 8 + half * 4) = o;
    }
  }
}

// ---------------- kernel 2: routing probabilities (f32 exact) ----------------
__global__ void __launch_bounds__(256) routing_kernel(
    const float* __restrict__ x, const float* __restrict__ Wd,
    const float* __restrict__ bd, float* __restrict__ rt) {
  __shared__ float xs[4][KD];
  __shared__ float sdp[4][64];
  const int tid = threadIdx.x;
  const int b0 = blockIdx.x * 4;
  const float4* xsrc = (const float4*)(x + (size_t)b0 * KD);
  float4* xdst = (float4*)&xs[0][0];
  for (int i = tid; i < KD; i += 256) xdst[i] = xsrc[i];
  __syncthreads();
  const int wv = tid >> 6, ln = tid & 63;
  const int b = b0 + wv;
  if (ln < 63) {
    const float4* wrow = (const float4*)(Wd + (size_t)ln * KD);
    const float4* xr = (const float4*)&xs[wv][0];
    float4 a = {0.f, 0.f, 0.f, 0.f};
    for (int k = 0; k < KD / 4; ++k) {
      float4 w = wrow[k], xv = xr[k];
      a.x += w.x * xv.x; a.y += w.y * xv.y; a.z += w.z * xv.z; a.w += w.w * xv.w;
    }
    float z = a.x + a.y + a.z + a.w + bd[ln];
    sdp[wv][ln] = 1.f / (1.f + __expf(-z));
  }
  __syncthreads();
  float prod = 1.f;
  int node = 0, index = ln;
  for (int d = 0; d < 6; ++d) {
    float pv = sdp[wv][node];
    prod *= (index & 1) ? (1.f - pv) : pv;
    node = node * 2 + 1 + (index & 1);
    index >>= 1;
  }
  rt[(size_t)b * NLEAF + ln] = prod;
}

// ---- kernel 3: 256x256 bf16 GEMM; A direct-from-packed-global to regs, ----
// ---- B via LDS ring of 4 x 16KB kk-halves, counted vmcnt(10), 1 bar/step ---
#define GBODY(CUR, NXT, S, VMASM, LAST)                                     \
  {                                                                          \
    if (!(LAST)) {                                                           \
      _Pragma("unroll")                                                      \
      for (int mi = 0; mi < 8; ++mi)                                         \
        NXT[mi] = *(const bf16x8*)(apL +                                     \
            ((size_t)((S) + 1) * 128 + rf0 + mi) * 512);                     \
    }                                                                        \
    if ((S) + 2 < 32) STAGE_B((S) + 2);                                      \
    asm volatile(VMASM ::: "memory");                                        \
    asm volatile("s_barrier" ::: "memory");                                  \
    const char* bbuf = smem + ((S) & 3) * 16384;                             \
    bf16x8 bfr[4];                                                           \
    _Pragma("unroll")                                                        \
    for (int ni = 0; ni < 4; ++ni)                                           \
      bfr[ni] = *(const bf16x8*)(bbuf + offB[ni]);                           \
    __builtin_amdgcn_s_setprio(1);                                           \
    _Pragma("unroll")                                                        \
    for (int mi = 0; mi < 8; ++mi)                                           \
      _Pragma("unroll")                                                      \
      for (int ni = 0; ni < 4; ++ni)                                         \
        acc[mi][ni] = __builtin_amdgcn_mfma_f32_16x16x32_bf16(               \
            CUR[mi], bfr[ni], acc[mi][ni], 0, 0, 0);                         \
    __builtin_amdgcn_s_setprio(0);                                           \
  }

__global__ void __launch_bounds__(512, 2) gemm_kernel(
    const unsigned short* __restrict__ Ap, const unsigned short* __restrict__ B,
    _Float16* __restrict__ C, int ntile) {
  extern __shared__ char smem[];   // 4 x 16KB B kk-half buffers
  const int tid = threadIdx.x;
  const int w = tid >> 6, ln = tid & 63;
  const int wm = w >> 2, wn = w & 3;
  const int g = ln >> 4, r16 = ln & 15;
  const int bid = blockIdx.x;
  const int j = bid >> 3;                       // XCD-chunked swizzle
  const int bm = (j & 7) * BM;
  const int bn = (((j >> 3) << 3) + (bid & 7)) * BN;
  const long long ldc = (long long)ntile * 256;

  // B staging (proven path): 256 rows x 32k halves, 64B rows, chunk-XOR swz
  const int rS = tid >> 2;
  const int cS = tid & 3;
  const int csrc = cS ^ ((rS >> 1) & 3);
  const unsigned short* gb0 = B + (size_t)(bn + rS) * KD + csrc * 8;
  const unsigned short* gb1 = gb0 + (size_t)128 * KD;
  const int ldsw = w * 1024;

  auto STAGE_B = [&](int s) {     // kk-half s -> ring buf s&3
    char* base = smem + (s & 3) * 16384;
    const size_t ko = (size_t)s * 32;
    gload_lds16(gb0 + ko, base + ldsw);
    gload_lds16(gb1 + ko, base + 8192 + ldsw);
  };

  int offB[4];
#pragma unroll
  for (int ni = 0; ni < 4; ++ni) {
    const int row = wn * 64 + ni * 16 + r16;
    offB[ni] = row * 64 + (g ^ ((row >> 1) & 3)) * 16;
  }

  // A packed fragments: frag = s*128 + rf0 + mi; per-lane 16B at ln*8 ushorts
  const int rf0 = (bm >> 4) + wm * 8;
  const unsigned short* apL = Ap + (size_t)ln * 8;

  f32x4 acc[8][4];
#pragma unroll
  for (int mi = 0; mi < 8; ++mi)
#pragma unroll
    for (int ni = 0; ni < 4; ++ni) acc[mi][ni] = (f32x4){0.f, 0.f, 0.f, 0.f};

  bf16x8 aE[8], aO[8];
  // prologue: B0, A0 -> aE, B1   (queue = 12 vmem ops)
  STAGE_B(0);
#pragma unroll
  for (int mi = 0; mi < 8; ++mi)
    aE[mi] = *(const bf16x8*)(apL + ((size_t)rf0 + mi) * 512);
  STAGE_B(1);

  for (int u = 0; u < 15; ++u) {
    GBODY(aE, aO, 2 * u,     "s_waitcnt vmcnt(10)", false);
    GBODY(aO, aE, 2 * u + 1, "s_waitcnt vmcnt(10)", false);
  }
  GBODY(aE, aO, 30, "s_waitcnt vmcnt(8)", false);
  GBODY(aO, aE, 31, "s_waitcnt vmcnt(0)", true);

  // epilogue: C/D layout col=r16, row=g*4+q (proven mapping)
#pragma unroll
  for (int mi = 0; mi < 8; ++mi)
#pragma unroll
    for (int q = 0; q < 4; ++q) {
      const long long grow = bm + wm * 128 + mi * 16 + g * 4 + q;
#pragma unroll
      for (int ni = 0; ni < 4; ++ni) {
        const int gcol = bn + wn * 64 + ni * 16 + r16;
        C[grow * ldc + gcol] = (_Float16)acc[mi][ni][q];
      }
    }
}

// ------- kernel 4: softmax (no-max-sub, |logit|<~5) + weighted reduce -------
__global__ void __launch_bounds__(256) smax_kernel(
    const _Float16* __restrict__ Cg, const float* __restrict__ rt,
    const float* __restrict__ bl, float* __restrict__ out,
    int lpg, int l0, int first) {
  __shared__ float reds[2][2][4];
  __shared__ float rts[64];
  const int tid = threadIdx.x;
  const int b = blockIdx.x;
  const int w = tid >> 6, ln = tid & 63;
  const int c0 = tid * 4;
  if (tid < lpg) rts[tid] = rt[(size_t)b * NLEAF + l0 + tid];
  __syncthreads();
  float oacc[4] = {0.f, 0.f, 0.f, 0.f};
  const long long ldc = (long long)lpg * ND;

  for (int jj = 0; jj < lpg; jj += 2) {
    const int par = (jj >> 1) & 1;
    const f16x4 h0 = *(const f16x4*)(Cg + (size_t)b * ldc + jj * ND + c0);
    const f16x4 h1 = *(const f16x4*)(Cg + (size_t)b * ldc + (jj + 1) * ND + c0);
    const float4 bv0 = *(const float4*)(bl + (size_t)(l0 + jj) * ND + c0);
    const float4 bv1 = *(const float4*)(bl + (size_t)(l0 + jj + 1) * ND + c0);
    float e0[4], e1[4], s0 = 0.f, s1 = 0.f;
    e0[0] = __expf((float)h0[0] + bv0.x); e0[1] = __expf((float)h0[1] + bv0.y);
    e0[2] = __expf((float)h0[2] + bv0.z); e0[3] = __expf((float)h0[3] + bv0.w);
    e1[0] = __expf((float)h1[0] + bv1.x); e1[1] = __expf((float)h1[1] + bv1.y);
    e1[2] = __expf((float)h1[2] + bv1.z); e1[3] = __expf((float)h1[3] + bv1.w);
#pragma unroll
    for (int k = 0; k < 4; ++k) { s0 += e0[k]; s1 += e1[k]; }
#pragma unroll
    for (int off = 1; off < 64; off <<= 1) {
      s0 += __shfl_xor(s0, off);
      s1 += __shfl_xor(s1, off);
    }
    if (ln == 0) { reds[par][0][w] = s0; reds[par][1][w] = s1; }
    __syncthreads();
    const float S0 = reds[par][0][0] + reds[par][0][1] + reds[par][0][2] + reds[par][0][3];
    const float S1 = reds[par][1][0] + reds[par][1][1] + reds[par][1][2] + reds[par][1][3];
    const float c0f = rts[jj] / S0;
    const float c1f = rts[jj + 1] / S1;
#pragma unroll
    for (int k = 0; k < 4; ++k) oacc[k] += c0f * e0[k] + c1f * e1[k];
  }

  float* orow = out + (size_t)b * ND + c0;
  if (first) {
    *(float4*)orow = (float4){oacc[0], oacc[1], oacc[2], oacc[3]};
  } else {
    float4 p = *(const float4*)orow;
    p.x += oacc[0]; p.y += oacc[1]; p.z += oacc[2]; p.w += oacc[3];
    *(float4*)orow = p;
  }
}

extern "C" void kernel_launch(void* const* d_in, const int* in_sizes, int n_in,
                              void* d_out, int out_size, void* d_ws, size_t ws_size,
                              hipStream_t stream) {
  const float* x  = (const float*)d_in[0];
  const float* Wd = (const float*)d_in[1];
  const float* bd = (const float*)d_in[2];
  const float* Wl = (const float*)d_in[3];
  const float* bl = (const float*)d_in[4];
  float* out = (float*)d_out;
  char* ws = (char*)d_ws;
  unsigned short* wlb = (unsigned short*)(ws + WLB_OFF);
  unsigned short* xp  = (unsigned short*)(ws + XP_OFF);
  float* rt           = (float*)(ws + RT_OFF);
  _Float16* lg        = (_Float16*)(ws + LG_OFF);

  convert_kernel<<<2048, 256, 0, stream>>>(Wl, x, wlb, xp);
  routing_kernel<<<BATCH / 4, 256, 0, stream>>>(x, Wd, bd, rt);
  hipFuncSetAttribute((const void*)gemm_kernel,
                      hipFuncAttributeMaxDynamicSharedMemorySize, 65536);

  const int ngrp = (ws_size >= LG_OFF + (size_t)BATCH * NLEAF * ND * 2) ? 1 : 4;
  const int lpg = NLEAF / ngrp;
  const int ntile = lpg * (ND / BN);
  for (int grp = 0; grp < ngrp; ++grp) {
    gemm_kernel<<<8 * ntile, 512, 65536, stream>>>(
        xp, wlb + (size_t)grp * lpg * ND * KD, lg, ntile);
    smax_kernel<<<BATCH, 256, 0, stream>>>(lg, rt, bl, out,
                                           lpg, grp * lpg, grp == 0);
  }
}

// Round 8
// 534.331 us; speedup vs baseline: 1.0369x; 1.0369x over previous
//
#include <hip/hip_runtime.h>
#include <hip/hip_bf16.h>

#define BATCH 2048
#define KD 1024
#define ND 1024
#define NLEAF 64
#define BM 128
#define BN 256
// GEMM runs 32 kk-steps of K=32 each

typedef __attribute__((ext_vector_type(8))) short bf16x8;
typedef __attribute__((ext_vector_type(4))) float f32x4;
typedef __attribute__((ext_vector_type(4))) _Float16 f16x4;

// workspace layout (bytes)
#define WLB_OFF 0ULL                 // B (Wl) bf16 row-major, 128 MB
#define XP_OFF  134217728ULL         // A (x) bf16 fragment-packed, 4 MB
#define RT_OFF  138412032ULL         // routing 512 KB
#define LG_OFF  138936320ULL         // logits fp16 (268 MB full / 64 MB grouped)

__device__ __forceinline__ unsigned short f2bf(float f) {
  unsigned int u = __float_as_uint(f);
  u += 0x7fffu + ((u >> 16) & 1u);
  return (unsigned short)(u >> 16);
}

__device__ __forceinline__ void gload_lds16(const void* g, void* l) {
  __builtin_amdgcn_global_load_lds(
      (const __attribute__((address_space(1))) unsigned int*)g,
      (__attribute__((address_space(3))) unsigned int*)l, 16, 0, 0);
}

// -------- kernel 1: f32 -> bf16; Wl row-major, x fragment-packed -----------
// A-pack (verified round 7): element (row,k) ->
//   f = (k>>5)*128 + (row>>4); lane = ((k>>3)&3)*16 + (row&15); e = k&7
__global__ void __launch_bounds__(256) convert_kernel(
    const float* __restrict__ Wl, const float* __restrict__ x,
    unsigned short* __restrict__ wlb, unsigned short* __restrict__ xp) {
  const long long WL4 = 16777216LL;
  const long long XJ  = 524288LL;
  long long i = (long long)blockIdx.x * 256 + threadIdx.x;
  const long long stride = (long long)gridDim.x * 256;
  for (; i < WL4 + XJ; i += stride) {
    if (i < WL4) {
      float4 v = ((const float4*)Wl)[i];
      ushort4 o;
      o.x = f2bf(v.x); o.y = f2bf(v.y); o.z = f2bf(v.z); o.w = f2bf(v.w);
      ((ushort4*)wlb)[i] = o;
    } else {
      const long long jj = i - WL4;
      const int pt = (int)(jj >> 1), half = (int)(jj & 1);
      const int f = pt >> 6, l = pt & 63;
      const int row = (f & 127) * 16 + (l & 15);
      const int k0 = (f >> 7) * 32 + (l >> 4) * 8 + half * 4;
      float4 v = *(const float4*)(x + (size_t)row * KD + k0);
      ushort4 o;
      o.x = f2bf(v.x); o.y = f2bf(v.y); o.z = f2bf(v.z); o.w = f2bf(v.w);
      *(ushort4*)(xp + (size_t)f * 512 + l * 8 + half * 4) = o;
    }
  }
}

// ---------------- kernel 2: routing probabilities (f32 exact) ----------------
__global__ void __launch_bounds__(256) routing_kernel(
    const float* __restrict__ x, const float* __restrict__ Wd,
    const float* __restrict__ bd, float* __restrict__ rt) {
  __shared__ float xs[4][KD];
  __shared__ float sdp[4][64];
  const int tid = threadIdx.x;
  const int b0 = blockIdx.x * 4;
  const float4* xsrc = (const float4*)(x + (size_t)b0 * KD);
  float4* xdst = (float4*)&xs[0][0];
  for (int i = tid; i < KD; i += 256) xdst[i] = xsrc[i];
  __syncthreads();
  const int wv = tid >> 6, ln = tid & 63;
  const int b = b0 + wv;
  if (ln < 63) {
    const float4* wrow = (const float4*)(Wd + (size_t)ln * KD);
    const float4* xr = (const float4*)&xs[wv][0];
    float4 a = {0.f, 0.f, 0.f, 0.f};
    for (int k = 0; k < KD / 4; ++k) {
      float4 w = wrow[k], xv = xr[k];
      a.x += w.x * xv.x; a.y += w.y * xv.y; a.z += w.z * xv.z; a.w += w.w * xv.w;
    }
    float z = a.x + a.y + a.z + a.w + bd[ln];
    sdp[wv][ln] = 1.f / (1.f + __expf(-z));
  }
  __syncthreads();
  float prod = 1.f;
  int node = 0, index = ln;
  for (int d = 0; d < 6; ++d) {
    float pv = sdp[wv][node];
    prod *= (index & 1) ? (1.f - pv) : pv;
    node = node * 2 + 1 + (index & 1);
    index >>= 1;
  }
  rt[(size_t)b * NLEAF + ln] = prod;
}

// ---- kernel 3: 128x256 bf16 GEMM, ZERO barriers. 4 waves; each wave owns ----
// ---- 128x64 output, a private 4-slot B-ring in LDS, and syncs only via  ----
// ---- its own counted vmcnt. A from packed global (verified round 7).    ----
#define GBODY(CUR, NXT, S, VMASM, LAST)                                      \
  {                                                                          \
    if (!(LAST)) {                                                           \
      _Pragma("unroll")                                                      \
      for (int mi = 0; mi < 8; ++mi)                                         \
        NXT[mi] = *(const bf16x8*)(apL +                                     \
            ((size_t)((S) + 1) * 128 + rf0 + mi) * 512);                     \
    }                                                                        \
    if ((S) + 3 < 32) STAGE_B((S) + 3);                                      \
    asm volatile(VMASM ::: "memory");                                        \
    const char* bbuf = myB + (((S) & 3) * 4096);                             \
    bf16x8 bfr[4];                                                           \
    _Pragma("unroll")                                                        \
    for (int ni = 0; ni < 4; ++ni)                                           \
      bfr[ni] = *(const bf16x8*)(bbuf + offB[ni]);                           \
    asm volatile("s_waitcnt lgkmcnt(0)" ::: "memory");                       \
    __builtin_amdgcn_sched_barrier(0);                                       \
    __builtin_amdgcn_s_setprio(1);                                           \
    _Pragma("unroll")                                                        \
    for (int mi = 0; mi < 8; ++mi)                                           \
      _Pragma("unroll")                                                      \
      for (int ni = 0; ni < 4; ++ni)                                         \
        acc[mi][ni] = __builtin_amdgcn_mfma_f32_16x16x32_bf16(               \
            CUR[mi], bfr[ni], acc[mi][ni], 0, 0, 0);                         \
    __builtin_amdgcn_s_setprio(0);                                           \
  }

__global__ void __launch_bounds__(256, 2) gemm_kernel(
    const unsigned short* __restrict__ Ap, const unsigned short* __restrict__ B,
    _Float16* __restrict__ C, int ntile) {
  extern __shared__ char smem[];   // 4 waves x 4 slots x 4 KB (private rings)
  const int tid = threadIdx.x;
  const int w = tid >> 6, ln = tid & 63;
  const int g = ln >> 4, r16 = ln & 15;
  // bijective XCD-chunked swizzle (gridDim multiple of 8)
  const int bid = blockIdx.x;
  const int cpx = gridDim.x >> 3;
  const int wg = (bid & 7) * cpx + (bid >> 3);
  const int mt = wg & 15, nt = wg >> 4;
  const int bm = mt * BM;
  const int bn = nt * BN;
  const long long ldc = (long long)ntile * 256;

  // ---- B private staging: wave w stages rows bn + w*64 + (0..63) ----
  // thread ln covers rows it*16 + (ln>>2), chunk (ln&3); chunk-XOR on source.
  const int rB = ln >> 2;
  const int csrcB = (ln & 3) ^ ((rB >> 1) & 3);   // row>>1 mod4 invariant in it
  const unsigned short* gbw =
      B + (size_t)(bn + w * 64 + rB) * KD + csrcB * 8;
  char* myB = smem + w * 16384;

  auto STAGE_B = [&](int s) {     // kk-step s -> private slot s&3
    char* base = myB + ((s & 3) * 4096);
    const size_t ko = (size_t)s * 32;
#pragma unroll
    for (int it = 0; it < 4; ++it)
      gload_lds16(gbw + (size_t)it * 16 * KD + ko, base + it * 1024);
  };

  // ds_read offsets within a slot (64B rows, read-side swizzle)
  int offB[4];
#pragma unroll
  for (int ni = 0; ni < 4; ++ni) {
    const int lr = ni * 16 + r16;
    offB[ni] = lr * 64 + (g ^ ((lr >> 1) & 3)) * 16;
  }

  // A packed fragments: frag = s*128 + rf0 + mi; per-lane 16B at ln*8
  const int rf0 = bm >> 4;
  const unsigned short* apL = Ap + (size_t)ln * 8;

  f32x4 acc[8][4];
#pragma unroll
  for (int mi = 0; mi < 8; ++mi)
#pragma unroll
    for (int ni = 0; ni < 4; ++ni) acc[mi][ni] = (f32x4){0.f, 0.f, 0.f, 0.f};

  bf16x8 aE[8], aO[8];
  // prologue: B0, A0 -> aE, B1, B2   (queue = 4+8+4+4 = 20)
  STAGE_B(0);
#pragma unroll
  for (int mi = 0; mi < 8; ++mi)
    aE[mi] = *(const bf16x8*)(apL + ((size_t)rf0 + mi) * 512);
  STAGE_B(1);
  STAGE_B(2);

  for (int u = 0; u < 14; ++u) {
    GBODY(aE, aO, 2 * u,     "s_waitcnt vmcnt(20)", false);
    GBODY(aO, aE, 2 * u + 1, "s_waitcnt vmcnt(20)", false);
  }
  GBODY(aE, aO, 28, "s_waitcnt vmcnt(20)", false);
  GBODY(aO, aE, 29, "s_waitcnt vmcnt(16)", false);
  GBODY(aE, aO, 30, "s_waitcnt vmcnt(12)", false);
  GBODY(aO, aE, 31, "s_waitcnt vmcnt(0)",  true);

  // epilogue: C/D layout col=r16, row=g*4+q (proven mapping)
#pragma unroll
  for (int mi = 0; mi < 8; ++mi)
#pragma unroll
    for (int q = 0; q < 4; ++q) {
      const long long grow = bm + mi * 16 + g * 4 + q;
#pragma unroll
      for (int ni = 0; ni < 4; ++ni) {
        const int gcol = bn + w * 64 + ni * 16 + r16;
        C[grow * ldc + gcol] = (_Float16)acc[mi][ni][q];
      }
    }
}

// ------- kernel 4: softmax (no-max-sub, |logit|<~5) + weighted reduce -------
__global__ void __launch_bounds__(256) smax_kernel(
    const _Float16* __restrict__ Cg, const float* __restrict__ rt,
    const float* __restrict__ bl, float* __restrict__ out,
    int lpg, int l0, int first) {
  __shared__ float reds[2][2][4];
  __shared__ float rts[64];
  const int tid = threadIdx.x;
  const int b = blockIdx.x;
  const int w = tid >> 6, ln = tid & 63;
  const int c0 = tid * 4;
  if (tid < lpg) rts[tid] = rt[(size_t)b * NLEAF + l0 + tid];
  __syncthreads();
  float oacc[4] = {0.f, 0.f, 0.f, 0.f};
  const long long ldc = (long long)lpg * ND;

  for (int jj = 0; jj < lpg; jj += 2) {
    const int par = (jj >> 1) & 1;
    const f16x4 h0 = *(const f16x4*)(Cg + (size_t)b * ldc + jj * ND + c0);
    const f16x4 h1 = *(const f16x4*)(Cg + (size_t)b * ldc + (jj + 1) * ND + c0);
    const float4 bv0 = *(const float4*)(bl + (size_t)(l0 + jj) * ND + c0);
    const float4 bv1 = *(const float4*)(bl + (size_t)(l0 + jj + 1) * ND + c0);
    float e0[4], e1[4], s0 = 0.f, s1 = 0.f;
    e0[0] = __expf((float)h0[0] + bv0.x); e0[1] = __expf((float)h0[1] + bv0.y);
    e0[2] = __expf((float)h0[2] + bv0.z); e0[3] = __expf((float)h0[3] + bv0.w);
    e1[0] = __expf((float)h1[0] + bv1.x); e1[1] = __expf((float)h1[1] + bv1.y);
    e1[2] = __expf((float)h1[2] + bv1.z); e1[3] = __expf((float)h1[3] + bv1.w);
#pragma unroll
    for (int k = 0; k < 4; ++k) { s0 += e0[k]; s1 += e1[k]; }
#pragma unroll
    for (int off = 1; off < 64; off <<= 1) {
      s0 += __shfl_xor(s0, off);
      s1 += __shfl_xor(s1, off);
    }
    if (ln == 0) { reds[par][0][w] = s0; reds[par][1][w] = s1; }
    __syncthreads();
    const float S0 = reds[par][0][0] + reds[par][0][1] + reds[par][0][2] + reds[par][0][3];
    const float S1 = reds[par][1][0] + reds[par][1][1] + reds[par][1][2] + reds[par][1][3];
    const float c0f = rts[jj] / S0;
    const float c1f = rts[jj + 1] / S1;
#pragma unroll
    for (int k = 0; k < 4; ++k) oacc[k] += c0f * e0[k] + c1f * e1[k];
  }

  float* orow = out + (size_t)b * ND + c0;
  if (first) {
    *(float4*)orow = (float4){oacc[0], oacc[1], oacc[2], oacc[3]};
  } else {
    float4 p = *(const float4*)orow;
    p.x += oacc[0]; p.y += oacc[1]; p.z += oacc[2]; p.w += oacc[3];
    *(float4*)orow = p;
  }
}

extern "C" void kernel_launch(void* const* d_in, const int* in_sizes, int n_in,
                              void* d_out, int out_size, void* d_ws, size_t ws_size,
                              hipStream_t stream) {
  const float* x  = (const float*)d_in[0];
  const float* Wd = (const float*)d_in[1];
  const float* bd = (const float*)d_in[2];
  const float* Wl = (const float*)d_in[3];
  const float* bl = (const float*)d_in[4];
  float* out = (float*)d_out;
  char* ws = (char*)d_ws;
  unsigned short* wlb = (unsigned short*)(ws + WLB_OFF);
  unsigned short* xp  = (unsigned short*)(ws + XP_OFF);
  float* rt           = (float*)(ws + RT_OFF);
  _Float16* lg        = (_Float16*)(ws + LG_OFF);

  convert_kernel<<<2048, 256, 0, stream>>>(Wl, x, wlb, xp);
  routing_kernel<<<BATCH / 4, 256, 0, stream>>>(x, Wd, bd, rt);
  hipFuncSetAttribute((const void*)gemm_kernel,
                      hipFuncAttributeMaxDynamicSharedMemorySize, 65536);

  const int ngrp = (ws_size >= LG_OFF + (size_t)BATCH * NLEAF * ND * 2) ? 1 : 4;
  const int lpg = NLEAF / ngrp;
  const int ntile = lpg * (ND / BN);       // n-tiles of 256
  for (int grp = 0; grp < ngrp; ++grp) {
    gemm_kernel<<<16 * ntile, 256, 65536, stream>>>(
        xp, wlb + (size_t)grp * lpg * ND * KD, lg, ntile);
    smax_kernel<<<BATCH, 256, 0, stream>>>(lg, rt, bl, out,
                                           lpg, grp * lpg, grp == 0);
  }
}

// Round 9
// 501.612 us; speedup vs baseline: 1.1045x; 1.0652x over previous
//
#include <hip/hip_runtime.h>
#include <hip/hip_bf16.h>

#define BATCH 2048
#define KD 1024
#define ND 1024
#define NLEAF 64
#define BM 256
#define BN 256
// 32 kk-steps of K=32

typedef __attribute__((ext_vector_type(8))) short bf16x8;
typedef __attribute__((ext_vector_type(4))) float f32x4;
typedef __attribute__((ext_vector_type(4))) _Float16 f16x4;

// workspace layout (bytes)
#define WLB_OFF 0ULL                 // B (Wl) bf16 row-major, 128 MB
#define XB_OFF  134217728ULL         // A (x) bf16 row-major, 4 MB
#define RT_OFF  138412032ULL         // routing 512 KB
#define LG_OFF  138936320ULL         // logits fp16 (268 MB full / 64 MB grouped)

__device__ __forceinline__ unsigned short f2bf(float f) {
  unsigned int u = __float_as_uint(f);
  u += 0x7fffu + ((u >> 16) & 1u);
  return (unsigned short)(u >> 16);
}

__device__ __forceinline__ void gload_lds16(const void* g, void* l) {
  __builtin_amdgcn_global_load_lds(
      (const __attribute__((address_space(1))) unsigned int*)g,
      (__attribute__((address_space(3))) unsigned int*)l, 16, 0, 0);
}

// ---------------- kernel 1: f32 -> bf16 conversion of Wl and x ----------------
__global__ void __launch_bounds__(256) convert_kernel(
    const float* __restrict__ Wl, const float* __restrict__ x,
    unsigned short* __restrict__ wlb, unsigned short* __restrict__ xb) {
  const long long WL4 = 16777216LL;
  const long long X4  = 524288LL;
  long long i = (long long)blockIdx.x * 256 + threadIdx.x;
  const long long stride = (long long)gridDim.x * 256;
  for (; i < WL4 + X4; i += stride) {
    float4 v;
    if (i < WL4) v = ((const float4*)Wl)[i];
    else         v = ((const float4*)x)[i - WL4];
    ushort4 o;
    o.x = f2bf(v.x); o.y = f2bf(v.y); o.z = f2bf(v.z); o.w = f2bf(v.w);
    if (i < WL4) ((ushort4*)wlb)[i] = o;
    else         ((ushort4*)xb)[i - WL4] = o;
  }
}

// ---------------- kernel 2: routing probabilities (f32 exact) ----------------
__global__ void __launch_bounds__(256) routing_kernel(
    const float* __restrict__ x, const float* __restrict__ Wd,
    const float* __restrict__ bd, float* __restrict__ rt) {
  __shared__ float xs[4][KD];
  __shared__ float sdp[4][64];
  const int tid = threadIdx.x;
  const int b0 = blockIdx.x * 4;
  const float4* xsrc = (const float4*)(x + (size_t)b0 * KD);
  float4* xdst = (float4*)&xs[0][0];
  for (int i = tid; i < KD; i += 256) xdst[i] = xsrc[i];
  __syncthreads();
  const int wv = tid >> 6, ln = tid & 63;
  const int b = b0 + wv;
  if (ln < 63) {
    const float4* wrow = (const float4*)(Wd + (size_t)ln * KD);
    const float4* xr = (const float4*)&xs[wv][0];
    float4 a = {0.f, 0.f, 0.f, 0.f};
    for (int k = 0; k < KD / 4; ++k) {
      float4 w = wrow[k], xv = xr[k];
      a.x += w.x * xv.x; a.y += w.y * xv.y; a.z += w.z * xv.z; a.w += w.w * xv.w;
    }
    float z = a.x + a.y + a.z + a.w + bd[ln];
    sdp[wv][ln] = 1.f / (1.f + __expf(-z));
  }
  __syncthreads();
  float prod = 1.f;
  int node = 0, index = ln;
  for (int d = 0; d < 6; ++d) {
    float pv = sdp[wv][node];
    prod *= (index & 1) ? (1.f - pv) : pv;
    node = node * 2 + 1 + (index & 1);
    index >>= 1;
  }
  rt[(size_t)b * NLEAF + ln] = prod;
}

// ------ kernel 3: 256x256 bf16 GEMM, 4-slot ring, REGISTER-DOUBLE-BUFFERED ----
// ------ fragments: ds_reads for step s+1 issued before MFMA(s)            ----
#define GBODY(CURA, CURB, NXTA, NXTB, S, VMASM, DOREAD)                      \
  {                                                                          \
    if ((S) + 3 < 32) STAGE((S) + 3);                                        \
    asm volatile(VMASM ::: "memory");                                        \
    asm volatile("s_waitcnt lgkmcnt(0)" ::: "memory");                       \
    asm volatile("s_barrier" ::: "memory");                                  \
    if (DOREAD) {                                                            \
      const char* nbuf = smem + (((S) + 1) & 3) * 32768;                     \
      _Pragma("unroll")                                                      \
      for (int mi = 0; mi < 8; ++mi)                                         \
        NXTA[mi] = *(const bf16x8*)(nbuf + offA[mi]);                        \
      _Pragma("unroll")                                                      \
      for (int ni = 0; ni < 4; ++ni)                                         \
        NXTB[ni] = *(const bf16x8*)(nbuf + 16384 + offB[ni]);                \
    }                                                                        \
    __builtin_amdgcn_sched_barrier(0);                                       \
    __builtin_amdgcn_s_setprio(1);                                           \
    _Pragma("unroll")                                                        \
    for (int mi = 0; mi < 8; ++mi)                                           \
      _Pragma("unroll")                                                      \
      for (int ni = 0; ni < 4; ++ni)                                         \
        acc[mi][ni] = __builtin_amdgcn_mfma_f32_16x16x32_bf16(               \
            CURA[mi], CURB[ni], acc[mi][ni], 0, 0, 0);                       \
    __builtin_amdgcn_s_setprio(0);                                           \
    __builtin_amdgcn_sched_barrier(0);                                       \
  }

__global__ void __launch_bounds__(512, 2) gemm_kernel(
    const unsigned short* __restrict__ A, const unsigned short* __restrict__ B,
    _Float16* __restrict__ C, int ntile) {
  extern __shared__ char smem[];   // 4 slots x 32 KB: {A 16K | B 16K}
  const int tid = threadIdx.x;
  const int w = tid >> 6, ln = tid & 63;
  const int wm = w >> 2, wn = w & 3;
  const int g = ln >> 4, r16 = ln & 15;
  const int bid = blockIdx.x;
  const int j = bid >> 3;                       // XCD-chunked swizzle
  const int bm = (j & 7) * BM;
  const int bn = (((j >> 3) << 3) + (bid & 7)) * BN;
  const long long ldc = (long long)ntile * 256;

  // staging: rows 0..127 (+128 second load), chunk-XOR on source
  const int rS = tid >> 2;
  const int cS = tid & 3;
  const int csrc = cS ^ ((rS >> 1) & 3);
  const unsigned short* ga0 = A + (size_t)(bm + rS) * KD + csrc * 8;
  const unsigned short* ga1 = ga0 + (size_t)128 * KD;
  const unsigned short* gb0 = B + (size_t)(bn + rS) * KD + csrc * 8;
  const unsigned short* gb1 = gb0 + (size_t)128 * KD;
  const int ldsw = w * 1024;                    // wave-uniform dest

  auto STAGE = [&](int t) {       // kk-step t -> slot t&3
    char* base = smem + (t & 3) * 32768;
    const size_t ko = (size_t)t * 32;
    gload_lds16(ga0 + ko, base + ldsw);
    gload_lds16(ga1 + ko, base + 8192 + ldsw);
    gload_lds16(gb0 + ko, base + 16384 + ldsw);
    gload_lds16(gb1 + ko, base + 24576 + ldsw);
  };

  // per-thread LDS read offsets (read-side swizzle), within 16 KB regions
  int offA[8], offB[4];
#pragma unroll
  for (int mi = 0; mi < 8; ++mi) {
    const int row = wm * 128 + mi * 16 + r16;
    offA[mi] = row * 64 + (g ^ ((row >> 1) & 3)) * 16;
  }
#pragma unroll
  for (int ni = 0; ni < 4; ++ni) {
    const int row = wn * 64 + ni * 16 + r16;
    offB[ni] = row * 64 + (g ^ ((row >> 1) & 3)) * 16;
  }

  f32x4 acc[8][4];
#pragma unroll
  for (int mi = 0; mi < 8; ++mi)
#pragma unroll
    for (int ni = 0; ni < 4; ++ni) acc[mi][ni] = (f32x4){0.f, 0.f, 0.f, 0.f};

  bf16x8 aE[8], bE[4], aO[8], bO[4];

  // prologue: stage slots 0,1,2; publish slot 0; read frags(0) -> E
  STAGE(0); STAGE(1); STAGE(2);
  asm volatile("s_waitcnt vmcnt(8)" ::: "memory");
  asm volatile("s_barrier" ::: "memory");
  {
    const char* nbuf = smem;
#pragma unroll
    for (int mi = 0; mi < 8; ++mi) aE[mi] = *(const bf16x8*)(nbuf + offA[mi]);
#pragma unroll
    for (int ni = 0; ni < 4; ++ni) bE[ni] = *(const bf16x8*)(nbuf + 16384 + offB[ni]);
  }

  for (int u = 0; u < 14; ++u) {
    GBODY(aE, bE, aO, bO, 2 * u,     "s_waitcnt vmcnt(8)", 1);
    GBODY(aO, bO, aE, bE, 2 * u + 1, "s_waitcnt vmcnt(8)", 1);
  }
  GBODY(aE, bE, aO, bO, 28, "s_waitcnt vmcnt(8)", 1);
  GBODY(aO, bO, aE, bE, 29, "s_waitcnt vmcnt(4)", 1);
  GBODY(aE, bE, aO, bO, 30, "s_waitcnt vmcnt(0)", 1);
  GBODY(aO, bO, aE, bE, 31, "s_waitcnt vmcnt(0)", 0);

  // epilogue: C/D layout col=r16, row=g*4+q (proven mapping)
#pragma unroll
  for (int mi = 0; mi < 8; ++mi)
#pragma unroll
    for (int q = 0; q < 4; ++q) {
      const long long grow = bm + wm * 128 + mi * 16 + g * 4 + q;
#pragma unroll
      for (int ni = 0; ni < 4; ++ni) {
        const int gcol = bn + wn * 64 + ni * 16 + r16;
        C[grow * ldc + gcol] = (_Float16)acc[mi][ni][q];
      }
    }
}

// ------- kernel 4: softmax (no-max-sub, |logit|<~5) + weighted reduce -------
__global__ void __launch_bounds__(256) smax_kernel(
    const _Float16* __restrict__ Cg, const float* __restrict__ rt,
    const float* __restrict__ bl, float* __restrict__ out,
    int lpg, int l0, int first) {
  __shared__ float reds[2][2][4];
  __shared__ float rts[64];
  const int tid = threadIdx.x;
  const int b = blockIdx.x;
  const int w = tid >> 6, ln = tid & 63;
  const int c0 = tid * 4;
  if (tid < lpg) rts[tid] = rt[(size_t)b * NLEAF + l0 + tid];
  __syncthreads();
  float oacc[4] = {0.f, 0.f, 0.f, 0.f};
  const long long ldc = (long long)lpg * ND;

  for (int jj = 0; jj < lpg; jj += 2) {
    const int par = (jj >> 1) & 1;
    const f16x4 h0 = *(const f16x4*)(Cg + (size_t)b * ldc + jj * ND + c0);
    const f16x4 h1 = *(const f16x4*)(Cg + (size_t)b * ldc + (jj + 1) * ND + c0);
    const float4 bv0 = *(const float4*)(bl + (size_t)(l0 + jj) * ND + c0);
    const float4 bv1 = *(const float4*)(bl + (size_t)(l0 + jj + 1) * ND + c0);
    float e0[4], e1[4], s0 = 0.f, s1 = 0.f;
    e0[0] = __expf((float)h0[0] + bv0.x); e0[1] = __expf((float)h0[1] + bv0.y);
    e0[2] = __expf((float)h0[2] + bv0.z); e0[3] = __expf((float)h0[3] + bv0.w);
    e1[0] = __expf((float)h1[0] + bv1.x); e1[1] = __expf((float)h1[1] + bv1.y);
    e1[2] = __expf((float)h1[2] + bv1.z); e1[3] = __expf((float)h1[3] + bv1.w);
#pragma unroll
    for (int k = 0; k < 4; ++k) { s0 += e0[k]; s1 += e1[k]; }
#pragma unroll
    for (int off = 1; off < 64; off <<= 1) {
      s0 += __shfl_xor(s0, off);
      s1 += __shfl_xor(s1, off);
    }
    if (ln == 0) { reds[par][0][w] = s0; reds[par][1][w] = s1; }
    __syncthreads();
    const float S0 = reds[par][0][0] + reds[par][0][1] + reds[par][0][2] + reds[par][0][3];
    const float S1 = reds[par][1][0] + reds[par][1][1] + reds[par][1][2] + reds[par][1][3];
    const float c0f = rts[jj] / S0;
    const float c1f = rts[jj + 1] / S1;
#pragma unroll
    for (int k = 0; k < 4; ++k) oacc[k] += c0f * e0[k] + c1f * e1[k];
  }

  float* orow = out + (size_t)b * ND + c0;
  if (first) {
    *(float4*)orow = (float4){oacc[0], oacc[1], oacc[2], oacc[3]};
  } else {
    float4 p = *(const float4*)orow;
    p.x += oacc[0]; p.y += oacc[1]; p.z += oacc[2]; p.w += oacc[3];
    *(float4*)orow = p;
  }
}

extern "C" void kernel_launch(void* const* d_in, const int* in_sizes, int n_in,
                              void* d_out, int out_size, void* d_ws, size_t ws_size,
                              hipStream_t stream) {
  const float* x  = (const float*)d_in[0];
  const float* Wd = (const float*)d_in[1];
  const float* bd = (const float*)d_in[2];
  const float* Wl = (const float*)d_in[3];
  const float* bl = (const float*)d_in[4];
  float* out = (float*)d_out;
  char* ws = (char*)d_ws;
  unsigned short* wlb = (unsigned short*)(ws + WLB_OFF);
  unsigned short* xb  = (unsigned short*)(ws + XB_OFF);
  float* rt           = (float*)(ws + RT_OFF);
  _Float16* lg        = (_Float16*)(ws + LG_OFF);

  convert_kernel<<<2048, 256, 0, stream>>>(Wl, x, wlb, xb);
  routing_kernel<<<BATCH / 4, 256, 0, stream>>>(x, Wd, bd, rt);
  hipFuncSetAttribute((const void*)gemm_kernel,
                      hipFuncAttributeMaxDynamicSharedMemorySize, 131072);

  const int ngrp = (ws_size >= LG_OFF + (size_t)BATCH * NLEAF * ND * 2) ? 1 : 4;
  const int lpg = NLEAF / ngrp;
  const int ntile = lpg * (ND / BN);
  for (int grp = 0; grp < ngrp; ++grp) {
    gemm_kernel<<<8 * ntile, 512, 131072, stream>>>(
        xb, wlb + (size_t)grp * lpg * ND * KD, lg, ntile);
    smax_kernel<<<BATCH, 256, 0, stream>>>(lg, rt, bl, out,
                                           lpg, grp * lpg, grp == 0);
  }
}

// Round 10
// 498.026 us; speedup vs baseline: 1.1124x; 1.0072x over previous
//
#include <hip/hip_runtime.h>
#include <hip/hip_bf16.h>

#define BATCH 2048
#define KD 1024
#define ND 1024
#define NLEAF 64
#define BM 256
#define BN 256
// 32 kk-steps of K=32

typedef __attribute__((ext_vector_type(8))) short bf16x8;
typedef __attribute__((ext_vector_type(4))) float f32x4;
typedef __attribute__((ext_vector_type(8))) _Float16 f16x8;

// workspace layout (bytes)
#define WLB_OFF 0ULL                 // B (Wl) bf16 row-major, 128 MB
#define XB_OFF  134217728ULL         // A (x) bf16 row-major, 4 MB
#define RT_OFF  138412032ULL         // routing 512 KB
#define LG_OFF  138936320ULL         // logits fp16 (268 MB full / 64 MB grouped)

__device__ __forceinline__ unsigned short f2bf(float f) {
  unsigned int u = __float_as_uint(f);
  u += 0x7fffu + ((u >> 16) & 1u);
  return (unsigned short)(u >> 16);
}

__device__ __forceinline__ void gload_lds16(const void* g, void* l) {
  __builtin_amdgcn_global_load_lds(
      (const __attribute__((address_space(1))) unsigned int*)g,
      (__attribute__((address_space(3))) unsigned int*)l, 16, 0, 0);
}

// ---------------- kernel 1: f32 -> bf16 conversion of Wl and x ----------------
__global__ void __launch_bounds__(256) convert_kernel(
    const float* __restrict__ Wl, const float* __restrict__ x,
    unsigned short* __restrict__ wlb, unsigned short* __restrict__ xb) {
  const long long WL4 = 16777216LL;
  const long long X4  = 524288LL;
  long long i = (long long)blockIdx.x * 256 + threadIdx.x;
  const long long stride = (long long)gridDim.x * 256;
  for (; i < WL4 + X4; i += stride) {
    float4 v;
    if (i < WL4) v = ((const float4*)Wl)[i];
    else         v = ((const float4*)x)[i - WL4];
    ushort4 o;
    o.x = f2bf(v.x); o.y = f2bf(v.y); o.z = f2bf(v.z); o.w = f2bf(v.w);
    if (i < WL4) ((ushort4*)wlb)[i] = o;
    else         ((ushort4*)xb)[i - WL4] = o;
  }
}

// ---------------- kernel 2: routing probabilities (f32 exact) ----------------
__global__ void __launch_bounds__(256) routing_kernel(
    const float* __restrict__ x, const float* __restrict__ Wd,
    const float* __restrict__ bd, float* __restrict__ rt) {
  __shared__ float xs[4][KD];
  __shared__ float sdp[4][64];
  const int tid = threadIdx.x;
  const int b0 = blockIdx.x * 4;
  const float4* xsrc = (const float4*)(x + (size_t)b0 * KD);
  float4* xdst = (float4*)&xs[0][0];
  for (int i = tid; i < KD; i += 256) xdst[i] = xsrc[i];
  __syncthreads();
  const int wv = tid >> 6, ln = tid & 63;
  const int b = b0 + wv;
  if (ln < 63) {
    const float4* wrow = (const float4*)(Wd + (size_t)ln * KD);
    const float4* xr = (const float4*)&xs[wv][0];
    float4 a = {0.f, 0.f, 0.f, 0.f};
    for (int k = 0; k < KD / 4; ++k) {
      float4 w = wrow[k], xv = xr[k];
      a.x += w.x * xv.x; a.y += w.y * xv.y; a.z += w.z * xv.z; a.w += w.w * xv.w;
    }
    float z = a.x + a.y + a.z + a.w + bd[ln];
    sdp[wv][ln] = 1.f / (1.f + __expf(-z));
  }
  __syncthreads();
  float prod = 1.f;
  int node = 0, index = ln;
  for (int d = 0; d < 6; ++d) {
    float pv = sdp[wv][node];
    prod *= (index & 1) ? (1.f - pv) : pv;
    node = node * 2 + 1 + (index & 1);
    index >>= 1;
  }
  rt[(size_t)b * NLEAF + ln] = prod;
}

// ------ kernel 3: 256x256 bf16 GEMM, 4-slot ring, reg-dbuf frags, ------------
// ------ sched_group_barrier-forced {ds_read, 2xMFMA} interleave    ------------
#define GBODY(CURA, CURB, NXTA, NXTB, S, VMASM, DOREAD)                      \
  {                                                                          \
    if ((S) + 3 < 32) STAGE((S) + 3);                                        \
    asm volatile(VMASM ::: "memory");                                        \
    asm volatile("s_waitcnt lgkmcnt(0)" ::: "memory");                       \
    __builtin_amdgcn_sched_barrier(0);                                       \
    asm volatile("s_barrier" ::: "memory");                                  \
    __builtin_amdgcn_s_setprio(1);                                           \
    if (DOREAD) {                                                            \
      const char* nbuf = smem + (((S) + 1) & 3) * 32768;                     \
      _Pragma("unroll")                                                      \
      for (int mi = 0; mi < 8; ++mi)                                         \
        NXTA[mi] = *(const bf16x8*)(nbuf + offA[mi]);                        \
      _Pragma("unroll")                                                      \
      for (int ni = 0; ni < 4; ++ni)                                         \
        NXTB[ni] = *(const bf16x8*)(nbuf + 16384 + offB[ni]);                \
    }                                                                        \
    _Pragma("unroll")                                                        \
    for (int mi = 0; mi < 8; ++mi)                                           \
      _Pragma("unroll")                                                      \
      for (int ni = 0; ni < 4; ++ni)                                         \
        acc[mi][ni] = __builtin_amdgcn_mfma_f32_16x16x32_bf16(               \
            CURA[mi], CURB[ni], acc[mi][ni], 0, 0, 0);                       \
    if (DOREAD) {                                                            \
      _Pragma("unroll")                                                      \
      for (int r = 0; r < 12; ++r) {                                         \
        __builtin_amdgcn_sched_group_barrier(0x100, 1, 0); /* 1 DS_READ */   \
        __builtin_amdgcn_sched_group_barrier(0x008, 2, 0); /* 2 MFMA    */   \
      }                                                                      \
      __builtin_amdgcn_sched_group_barrier(0x008, 8, 0);   /* tail MFMA */   \
    }                                                                        \
    __builtin_amdgcn_s_setprio(0);                                           \
    __builtin_amdgcn_sched_barrier(0);                                       \
  }

__global__ void __launch_bounds__(512, 2) gemm_kernel(
    const unsigned short* __restrict__ A, const unsigned short* __restrict__ B,
    const float* __restrict__ blg, _Float16* __restrict__ C, int ntile) {
  extern __shared__ char smem[];   // 4 slots x 32 KB: {A 16K | B 16K}
  const int tid = threadIdx.x;
  const int w = tid >> 6, ln = tid & 63;
  const int wm = w >> 2, wn = w & 3;
  const int g = ln >> 4, r16 = ln & 15;
  const int bid = blockIdx.x;
  const int j = bid >> 3;                       // XCD-chunked swizzle
  const int bm = (j & 7) * BM;
  const int bn = (((j >> 3) << 3) + (bid & 7)) * BN;
  const long long ldc = (long long)ntile * 256;

  // staging: rows 0..127 (+128 second load), chunk-XOR on source
  const int rS = tid >> 2;
  const int cS = tid & 3;
  const int csrc = cS ^ ((rS >> 1) & 3);
  const unsigned short* ga0 = A + (size_t)(bm + rS) * KD + csrc * 8;
  const unsigned short* ga1 = ga0 + (size_t)128 * KD;
  const unsigned short* gb0 = B + (size_t)(bn + rS) * KD + csrc * 8;
  const unsigned short* gb1 = gb0 + (size_t)128 * KD;
  const int ldsw = w * 1024;                    // wave-uniform dest

  auto STAGE = [&](int t) {       // kk-step t -> slot t&3
    char* base = smem + (t & 3) * 32768;
    const size_t ko = (size_t)t * 32;
    gload_lds16(ga0 + ko, base + ldsw);
    gload_lds16(ga1 + ko, base + 8192 + ldsw);
    gload_lds16(gb0 + ko, base + 16384 + ldsw);
    gload_lds16(gb1 + ko, base + 24576 + ldsw);
  };

  // per-thread LDS read offsets (read-side swizzle), within 16 KB regions
  int offA[8], offB[4];
#pragma unroll
  for (int mi = 0; mi < 8; ++mi) {
    const int row = wm * 128 + mi * 16 + r16;
    offA[mi] = row * 64 + (g ^ ((row >> 1) & 3)) * 16;
  }
#pragma unroll
  for (int ni = 0; ni < 4; ++ni) {
    const int row = wn * 64 + ni * 16 + r16;
    offB[ni] = row * 64 + (g ^ ((row >> 1) & 3)) * 16;
  }

  f32x4 acc[8][4];
#pragma unroll
  for (int mi = 0; mi < 8; ++mi)
#pragma unroll
    for (int ni = 0; ni < 4; ++ni) acc[mi][ni] = (f32x4){0.f, 0.f, 0.f, 0.f};

  bf16x8 aE[8], bE[4], aO[8], bO[4];

  // prologue: stage slots 0,1,2; publish slot 0; read frags(0) -> E
  STAGE(0); STAGE(1); STAGE(2);
  asm volatile("s_waitcnt vmcnt(8)" ::: "memory");
  asm volatile("s_barrier" ::: "memory");
  {
    const char* nbuf = smem;
#pragma unroll
    for (int mi = 0; mi < 8; ++mi) aE[mi] = *(const bf16x8*)(nbuf + offA[mi]);
#pragma unroll
    for (int ni = 0; ni < 4; ++ni) bE[ni] = *(const bf16x8*)(nbuf + 16384 + offB[ni]);
  }

  for (int u = 0; u < 14; ++u) {
    GBODY(aE, bE, aO, bO, 2 * u,     "s_waitcnt vmcnt(8)", 1);
    GBODY(aO, bO, aE, bE, 2 * u + 1, "s_waitcnt vmcnt(8)", 1);
  }
  GBODY(aE, bE, aO, bO, 28, "s_waitcnt vmcnt(8)", 1);
  GBODY(aO, bO, aE, bE, 29, "s_waitcnt vmcnt(4)", 1);
  GBODY(aE, bE, aO, bO, 30, "s_waitcnt vmcnt(0)", 1);
  GBODY(aO, bO, aE, bE, 31, "s_waitcnt vmcnt(0)", 0);

  // epilogue: C/D layout col=r16, row=g*4+q; fuse +bl (f32, pre-quantize)
  const int lf = bn >> 10;                       // leaf within this group
  float blv[4];
#pragma unroll
  for (int ni = 0; ni < 4; ++ni)
    blv[ni] = blg[(size_t)lf * ND + (bn & 1023) + wn * 64 + ni * 16 + r16];
#pragma unroll
  for (int mi = 0; mi < 8; ++mi)
#pragma unroll
    for (int q = 0; q < 4; ++q) {
      const long long grow = bm + wm * 128 + mi * 16 + g * 4 + q;
#pragma unroll
      for (int ni = 0; ni < 4; ++ni) {
        const int gcol = bn + wn * 64 + ni * 16 + r16;
        C[grow * ldc + gcol] = (_Float16)(acc[mi][ni][q] + blv[ni]);
      }
    }
}

// ------- kernel 4: softmax + weighted reduce, 1 wave per batch row -------
// bl already fused into logits. 64 lanes x 16 cols; no LDS, no syncthreads.
__global__ void __launch_bounds__(256) smax_kernel(
    const _Float16* __restrict__ Cg, const float* __restrict__ rt,
    float* __restrict__ out, int lpg, int l0, int first) {
  const int tid = threadIdx.x;
  const int wv = tid >> 6, ln = tid & 63;
  const int b = blockIdx.x * 4 + wv;
  const long long ldc = (long long)lpg * ND;
  const _Float16* base = Cg + (size_t)b * ldc + ln * 8;
  const float rtv = (ln < lpg) ? rt[(size_t)b * NLEAF + l0 + ln] : 0.f;

  float oacc[16];
#pragma unroll
  for (int k = 0; k < 16; ++k) oacc[k] = 0.f;

  for (int jj = 0; jj < lpg; ++jj) {
    const f16x8 h0 = *(const f16x8*)(base + jj * ND);        // cols [ln*8, +8)
    const f16x8 h1 = *(const f16x8*)(base + jj * ND + 512);  // cols [512+ln*8, +8)
    float e[16], s = 0.f;
#pragma unroll
    for (int k = 0; k < 8; ++k) { e[k] = __expf((float)h0[k]); s += e[k]; }
#pragma unroll
    for (int k = 0; k < 8; ++k) { e[8 + k] = __expf((float)h1[k]); s += e[8 + k]; }
#pragma unroll
    for (int off = 1; off < 64; off <<= 1) s += __shfl_xor(s, off);
    const float coef = __shfl(rtv, jj) / s;
#pragma unroll
    for (int k = 0; k < 16; ++k) oacc[k] += coef * e[k];
  }

  float* o0 = out + (size_t)b * ND + ln * 8;
  if (first) {
    *(float4*)o0         = (float4){oacc[0], oacc[1], oacc[2], oacc[3]};
    *(float4*)(o0 + 4)   = (float4){oacc[4], oacc[5], oacc[6], oacc[7]};
    *(float4*)(o0 + 512) = (float4){oacc[8], oacc[9], oacc[10], oacc[11]};
    *(float4*)(o0 + 516) = (float4){oacc[12], oacc[13], oacc[14], oacc[15]};
  } else {
#pragma unroll
    for (int part = 0; part < 4; ++part) {
      float* p = o0 + (part >> 1) * 512 + (part & 1) * 4;
      float4 v = *(const float4*)p;
      v.x += oacc[part * 4 + 0]; v.y += oacc[part * 4 + 1];
      v.z += oacc[part * 4 + 2]; v.w += oacc[part * 4 + 3];
      *(float4*)p = v;
    }
  }
}

extern "C" void kernel_launch(void* const* d_in, const int* in_sizes, int n_in,
                              void* d_out, int out_size, void* d_ws, size_t ws_size,
                              hipStream_t stream) {
  const float* x  = (const float*)d_in[0];
  const float* Wd = (const float*)d_in[1];
  const float* bd = (const float*)d_in[2];
  const float* Wl = (const float*)d_in[3];
  const float* bl = (const float*)d_in[4];
  float* out = (float*)d_out;
  char* ws = (char*)d_ws;
  unsigned short* wlb = (unsigned short*)(ws + WLB_OFF);
  unsigned short* xb  = (unsigned short*)(ws + XB_OFF);
  float* rt           = (float*)(ws + RT_OFF);
  _Float16* lg        = (_Float16*)(ws + LG_OFF);

  convert_kernel<<<2048, 256, 0, stream>>>(Wl, x, wlb, xb);
  routing_kernel<<<BATCH / 4, 256, 0, stream>>>(x, Wd, bd, rt);
  hipFuncSetAttribute((const void*)gemm_kernel,
                      hipFuncAttributeMaxDynamicSharedMemorySize, 131072);

  const int ngrp = (ws_size >= LG_OFF + (size_t)BATCH * NLEAF * ND * 2) ? 1 : 4;
  const int lpg = NLEAF / ngrp;
  const int ntile = lpg * (ND / BN);
  for (int grp = 0; grp < ngrp; ++grp) {
    gemm_kernel<<<8 * ntile, 512, 131072, stream>>>(
        xb, wlb + (size_t)grp * lpg * ND * KD,
        bl + (size_t)grp * lpg * ND, lg, ntile);
    smax_kernel<<<BATCH / 4, 256, 0, stream>>>(lg, rt, out,
                                               lpg, grp * lpg, grp == 0);
  }
}